// Round 3
// baseline (32.701 us; speedup 1.0000x reference)
//
#include <hip/hip_runtime.h>
#include <math.h>

#define FFT_N   4096
#define THREADS 512
#define RH 0.70710678118654752f
#define NEG2PI_64   (-9.81747704246810387e-2f)   // -2*pi/64
#define NEG2PI_4096 (-1.53398078788564123e-3f)   // -2*pi/4096

__device__ __forceinline__ float2 cmul(float2 a, float2 b) {
    return make_float2(a.x * b.x - a.y * b.y, a.x * b.y + a.y * b.x);
}
__device__ __forceinline__ void bfly1(float2& a, float2& b) {          // w = 1
    float2 t = b;
    b = make_float2(a.x - t.x, a.y - t.y);
    a = make_float2(a.x + t.x, a.y + t.y);
}
__device__ __forceinline__ void bflyNi(float2& a, float2& b) {         // w = -i
    float2 t = make_float2(b.y, -b.x);
    b = make_float2(a.x - t.x, a.y - t.y);
    a = make_float2(a.x + t.x, a.y + t.y);
}
__device__ __forceinline__ void bflyW(float2& a, float2& b, float2 w) {
    float2 t = cmul(w, b);
    b = make_float2(a.x - t.x, a.y - t.y);
    a = make_float2(a.x + t.x, a.y + t.y);
}

// out[k] = sum_b in[b] * W8^{b*k}; natural input order, natural output order.
// (DIT network fed in bit-reversed register order; verified vs impulse.)
__device__ __forceinline__ void dft8(float2 v[8]) {
    float2 n0 = v[0], n1 = v[4], n2 = v[2], n3 = v[6];
    float2 n4 = v[1], n5 = v[5], n6 = v[3], n7 = v[7];
    bfly1(n0, n1); bfly1(n2, n3); bfly1(n4, n5); bfly1(n6, n7);
    bfly1(n0, n2); bflyNi(n1, n3); bfly1(n4, n6); bflyNi(n5, n7);
    const float2 w81 = make_float2(RH, -RH), w83 = make_float2(-RH, -RH);
    bfly1(n0, n4); bflyW(n1, n5, w81); bflyNi(n2, n6); bflyW(n3, n7, w83);
    v[0] = n0; v[1] = n1; v[2] = n2; v[3] = n3;
    v[4] = n4; v[5] = n5; v[6] = n6; v[7] = n7;
}

__device__ __forceinline__ float2 shflx(float2 v, int mask) {
    return make_float2(__shfl_xor(v.x, mask, 64), __shfl_xor(v.y, mask, 64));
}

// DIF DFT-8 across the lane-high-3-bit dimension (lane xor masks 32,16,8).
// Input natural in lh; output at lane lh is bin brev3(lh).
// s1/w1, s2/w2, s3: per-thread precomputed combine signs and effective twiddles.
__device__ __forceinline__ void lane_dif8(float2 v[8], float s1, float2 w1,
                                          float s2, float2 w2, float s3) {
    #pragma unroll
    for (int r = 0; r < 8; ++r) {
        float2 p = shflx(v[r], 32);
        float2 t = make_float2(fmaf(s1, v[r].x, p.x), fmaf(s1, v[r].y, p.y));
        v[r] = cmul(t, w1);
    }
    #pragma unroll
    for (int r = 0; r < 8; ++r) {
        float2 p = shflx(v[r], 16);
        float2 t = make_float2(fmaf(s2, v[r].x, p.x), fmaf(s2, v[r].y, p.y));
        v[r] = cmul(t, w2);
    }
    #pragma unroll
    for (int r = 0; r < 8; ++r) {
        float2 p = shflx(v[r], 8);
        v[r] = make_float2(fmaf(s3, v[r].x, p.x), fmaf(s3, v[r].y, p.y));
    }
}

__global__ __launch_bounds__(THREADS)
void fft4096_6464(const float* __restrict__ xre, const float* __restrict__ xim,
                  float* __restrict__ yre, float* __restrict__ yim)
{
    __shared__ float2 sd[FFT_N];   // 32 KB, one swizzled transpose buffer

    const int tid = threadIdx.x;
    const int w  = tid >> 6;        // wave id [0,8)
    const int l  = tid & 63;
    const int lh = l >> 3;          // lane-high 3 bits
    const int ll = l & 7;           // lane-low 3 bits
    const int rb = ((lh & 1) << 2) | (lh & 2) | ((lh >> 2) & 1);  // brev3(lh)
    const size_t off = (size_t)blockIdx.x * FFT_N;

    // Per-thread lane-DIF8 stage constants (identical for both passes).
    // stage1 (mask32): active if lh&4, twiddle W8^{lh&3}
    // stage2 (mask16): active if lh&2, twiddle W4^{lh&1}
    // stage3 (mask8):  active if lh&1, twiddle 1
    const int c = lh & 3;
    const float wx = (c == 0) ? 1.f : (c == 1) ? RH : (c == 2) ? 0.f : -RH;
    const float wy = (c == 0) ? 0.f : (c == 2) ? -1.f : -RH;
    const float2 w1 = (lh & 4) ? make_float2(wx, wy) : make_float2(1.f, 0.f);
    const float2 w2 = (lh & 2) ? ((lh & 1) ? make_float2(0.f, -1.f)
                                           : make_float2(1.f, 0.f))
                               : make_float2(1.f, 0.f);
    const float s1 = (lh & 4) ? -1.f : 1.f;
    const float s2 = (lh & 2) ? -1.f : 1.f;
    const float s3 = (lh & 1) ? -1.f : 1.f;

    // ---- Load: element n = n1 + 64*n2, n1 = 8w+ll, n2 = lh + 8r ----
    const int n1v  = 8 * w + ll;
    const int base = n1v + 64 * lh;
    const float* xr = xre + off;
    const float* xi = xim + off;
    float2 v[8];
    #pragma unroll
    for (int r = 0; r < 8; ++r) {
        v[r].x = xr[base + 512 * r];
        v[r].y = xi[base + 512 * r];
    }

    // ---- Pass A: FFT-64 over n2 ----
    dft8(v);                                   // A1 over slots (beta=n2h) -> kappa1
    #pragma unroll
    for (int r = 1; r < 8; ++r) {              // A2: W64^{n2l * kappa1}
        float sn, cs;
        __sincosf((float)(lh * r) * NEG2PI_64, &sn, &cs);
        v[r] = cmul(v[r], make_float2(cs, sn));
    }
    lane_dif8(v, s1, w1, s2, w2, s3);          // A3 over lanes -> kappa2 = brev3(lh)

    // ---- Inter-pass twiddle + transpose through LDS ----
    // k1 = kappa1 + 8*kappa2 = r + 8*rb ; value *= W4096^{n1*k1}
    #pragma unroll
    for (int r = 0; r < 8; ++r) {
        const int k1 = r + (rb << 3);
        float sn, cs;
        __sincosf((float)(n1v * k1) * NEG2PI_4096, &sn, &cs);
        float2 t = cmul(v[r], make_float2(cs, sn));
        const int g = 9 * ((k1 & 7) ^ (k1 >> 3));       // bank swizzle
        sd[(k1 << 6) | (n1v ^ g)] = t;
    }
    __syncthreads();
    {
        const int k1m = 8 * w + ll;                      // this thread's k1 for pass B
        const int gm  = 9 * ((k1m & 7) ^ (k1m >> 3));
        #pragma unroll
        for (int r = 0; r < 8; ++r) {                    // slot r = n1h, lane lh = n1l
            const int n1 = lh + 8 * r;
            v[r] = sd[(k1m << 6) | (n1 ^ gm)];
        }
    }

    // ---- Pass B: FFT-64 over n1 ----
    dft8(v);                                   // B1 over slots (beta=n1h) -> lambda1
    #pragma unroll
    for (int r = 1; r < 8; ++r) {              // B2: W64^{n1l * lambda1}
        float sn, cs;
        __sincosf((float)(lh * r) * NEG2PI_64, &sn, &cs);
        v[r] = cmul(v[r], make_float2(cs, sn));
    }
    lane_dif8(v, s1, w1, s2, w2, s3);          // B3 over lanes -> lambda2 = brev3(lh)

    // ---- Store: k = k1 + 64*(lambda1 + 8*lambda2) = (8w+ll) + 64r + 512*rb ----
    float* yr = yre + off;
    float* yi = yim + off;
    const int sb = 8 * w + ll + 512 * rb;
    #pragma unroll
    for (int r = 0; r < 8; ++r) {
        yr[sb + 64 * r] = v[r].x;
        yi[sb + 64 * r] = v[r].y;
    }
}

extern "C" void kernel_launch(void* const* d_in, const int* in_sizes, int n_in,
                              void* d_out, int out_size, void* d_ws, size_t ws_size,
                              hipStream_t stream) {
    const float* xre = (const float*)d_in[0];
    const float* xim = (const float*)d_in[1];
    const int total = in_sizes[0];          // B * N
    const int rows  = total / FFT_N;        // 2048
    float* yre = (float*)d_out;
    float* yim = yre + total;
    fft4096_6464<<<dim3(rows), dim3(THREADS), 0, stream>>>(xre, xim, yre, yim);
}